// Round 4
// baseline (218.650 us; speedup 1.0000x reference)
//
#include <hip/hip_runtime.h>

// RoPE: X (L=2048, D=4096, N=4) fp32 -> out same shape. Round 3 resubmit:
// rounds 1-3 failed at container acquisition (infra) -- no kernel evidence.
//
// half = D/2; theta[j] = 10000^(2j/D) (POSITIVE exponent per reference);
// ang[l][j] = fl32((l+1) * theta[j])  -- must match numpy's float32
// rounding: ulp(ang) ~ 2 rad at ang ~ 2e7, so the rounding IS the value.
// out[l, j]      = cos*x1 - sin*x2
// out[l, j+half] = sin*x1 + cos*x2
// N=4 innermost floats -> float4 per (l,d) element; fully coalesced.

#define L_DIM 2048
#define D_DIM 4096
#define HALF 2048

__global__ __launch_bounds__(256) void rope_kernel(const float4* __restrict__ X,
                                                   float4* __restrict__ out) {
    int idx = blockIdx.x * blockDim.x + threadIdx.x;   // 0 .. L*HALF-1
    int l = idx >> 11;          // idx / HALF
    int j = idx & (HALF - 1);   // idx % HALF

    // theta in double then cast: correctly-rounded float32 of 10000^(j/2048),
    // matching numpy float32 np.power. (double)j * (1.0/2048.0) is exact.
    double e = (double)j * (1.0 / 2048.0);
    float theta = (float)pow(10000.0, e);

    // Single float32 multiply, exactly as the reference computes ang.
    float pos = (float)(l + 1);
    float ang = pos * theta;

    float s, c;
    sincosf(ang, &s, &c);   // accurate OCML path (full-range reduction)

    int base = l * D_DIM + j;           // float4 index of x1
    float4 x1 = X[base];
    float4 x2 = X[base + HALF];

    float4 o1, o2;
    o1.x = c * x1.x - s * x2.x;
    o1.y = c * x1.y - s * x2.y;
    o1.z = c * x1.z - s * x2.z;
    o1.w = c * x1.w - s * x2.w;
    o2.x = s * x1.x + c * x2.x;
    o2.y = s * x1.y + c * x2.y;
    o2.z = s * x1.z + c * x2.z;
    o2.w = s * x1.w + c * x2.w;

    out[base] = o1;
    out[base + HALF] = o2;
}

extern "C" void kernel_launch(void* const* d_in, const int* in_sizes, int n_in,
                              void* d_out, int out_size, void* d_ws, size_t ws_size,
                              hipStream_t stream) {
    const float4* X = (const float4*)d_in[0];
    float4* out = (float4*)d_out;
    int threads = L_DIM * HALF;           // 4,194,304
    dim3 block(256);
    dim3 grid(threads / 256);             // 16384
    rope_kernel<<<grid, block, 0, stream>>>(X, out);
}